// Round 4
// baseline (329.615 us; speedup 1.0000x reference)
//
#include <hip/hip_runtime.h>

#define TB 4
#define TF 4096
#define DIN 1024
#define DK 128
#define M_TOT (TB * TF)  // 16384

typedef __attribute__((ext_vector_type(8))) short sh8;
typedef __attribute__((ext_vector_type(4))) float f32x4;

__device__ __forceinline__ unsigned short f2bf(float f) {
  unsigned int u = __builtin_bit_cast(unsigned int, f);
  u += 0x7FFFu + ((u >> 16) & 1u);
  return (unsigned short)(u >> 16);
}

// Wt[p][n][k] = bf16(W_p[k][n]);  p in {q,k,v}
__global__ __launch_bounds__(256) void prep_wt_kernel(
    const float* __restrict__ Wq, const float* __restrict__ Wk,
    const float* __restrict__ Wv, unsigned short* __restrict__ Wt) {
  int idx = blockIdx.x * 256 + threadIdx.x;  // [0, 3*128*1024)
  int p = idx >> 17;
  int r = idx & 0x1FFFF;
  int n = r >> 10;
  int k = r & 1023;
  const float* W = (p == 0) ? Wq : (p == 1) ? Wk : Wv;
  Wt[idx] = f2bf(W[k * DK + n]);
}

// Fused QKV projection. Block = 64 rows of x, 4 waves each own 32 output cols
// for all 3 projections. Q is pre-scaled by 1/sqrt(128). V stored transposed.
__global__ __launch_bounds__(256) void proj_kernel(
    const float* __restrict__ x,            // [M_TOT][DIN]
    const unsigned short* __restrict__ Wt,  // [3][DK][DIN] bf16
    const float* __restrict__ bq, const float* __restrict__ bk,
    const float* __restrict__ bv,
    unsigned short* __restrict__ Qb,  // [M_TOT][DK] bf16 (pre-scaled)
    unsigned short* __restrict__ Kb,  // [M_TOT][DK] bf16
    unsigned short* __restrict__ VT)  // [TB][DK][TF] bf16
{
  const int tid = threadIdx.x;
  const int wave = tid >> 6;
  const int lane = tid & 63;
  const int lr = lane & 15;
  const int lg = lane >> 4;
  const int m0 = blockIdx.x * 64;

  f32x4 acc[3][4][2];
  const f32x4 z4 = {0.f, 0.f, 0.f, 0.f};
#pragma unroll
  for (int p = 0; p < 3; ++p)
#pragma unroll
    for (int m = 0; m < 4; ++m)
#pragma unroll
      for (int n = 0; n < 2; ++n) acc[p][m][n] = z4;

  for (int k0 = 0; k0 < DIN; k0 += 32) {
    sh8 a[4];
#pragma unroll
    for (int m = 0; m < 4; ++m) {
      const float* xp = x + (size_t)(m0 + m * 16 + lr) * DIN + k0 + lg * 8;
      float4 f0 = *(const float4*)xp;
      float4 f1 = *(const float4*)(xp + 4);
      union { sh8 v; unsigned short u[8]; } U;
      U.u[0] = f2bf(f0.x); U.u[1] = f2bf(f0.y);
      U.u[2] = f2bf(f0.z); U.u[3] = f2bf(f0.w);
      U.u[4] = f2bf(f1.x); U.u[5] = f2bf(f1.y);
      U.u[6] = f2bf(f1.z); U.u[7] = f2bf(f1.w);
      a[m] = U.v;
    }
#pragma unroll
    for (int p = 0; p < 3; ++p) {
#pragma unroll
      for (int n = 0; n < 2; ++n) {
        const int col = wave * 32 + n * 16 + lr;
        sh8 b = *(const sh8*)(Wt + ((size_t)p * DK + col) * DIN + k0 + lg * 8);
#pragma unroll
        for (int m = 0; m < 4; ++m)
          acc[p][m][n] = __builtin_amdgcn_mfma_f32_16x16x32_bf16(
              a[m], b, acc[p][m][n], 0, 0, 0);
      }
    }
  }

  const float scale = 0.08838834764831845f;  // 1/sqrt(128)
  const int b_idx = m0 >> 12;
#pragma unroll
  for (int n = 0; n < 2; ++n) {
    const int col = wave * 32 + n * 16 + lr;
    const float add_q = bq[col];
    const float add_k = bk[col];
    const float add_v = bv[col];
#pragma unroll
    for (int m = 0; m < 4; ++m) {
      const int rowbase = m0 + m * 16 + lg * 4;
#pragma unroll
      for (int r = 0; r < 4; ++r) {
        Qb[(size_t)(rowbase + r) * DK + col] =
            f2bf((acc[0][m][n][r] + add_q) * scale);
        Kb[(size_t)(rowbase + r) * DK + col] = f2bf(acc[1][m][n][r] + add_k);
      }
      const int fbase = (m0 & (TF - 1)) + m * 16 + lg * 4;
      ushort4 pv;
      pv.x = f2bf(acc[2][m][n][0] + add_v);
      pv.y = f2bf(acc[2][m][n][1] + add_v);
      pv.z = f2bf(acc[2][m][n][2] + add_v);
      pv.w = f2bf(acc[2][m][n][3] + add_v);
      *(ushort4*)(VT + ((size_t)b_idx * DK + col) * TF + fbase) = pv;
    }
  }
}

// Flash attention, swapped-operand form, split-KV.
// Each wave owns 16 q-rows; lane owns q = lr after S^T = mfma(K,Q).
// No K/V LDS staging (tiles are L1/L2-resident), no barriers.
// O accumulated transposed: O^T[d][q], al/l/m lane-local.
template <int SPLIT>
__global__ __launch_bounds__(256) void attn_part_kernel(
    const unsigned short* __restrict__ Qb, const unsigned short* __restrict__ Kb,
    const unsigned short* __restrict__ VT, float* __restrict__ Opart,
    float* __restrict__ Mpart, float* __restrict__ Lpart,
    float* __restrict__ out) {
  constexpr int CHUNK = TF / SPLIT;
  const int tid = threadIdx.x;
  const int wave = tid >> 6;
  const int lane = tid & 63;
  const int lr = lane & 15;
  const int lg = lane >> 4;

  // XCD swizzle: 2 XCDs per batch so K/V (2 MB bf16/batch) stays L2-resident.
  const int bid = blockIdx.x;
  const int xcd = bid & 7;
  const int batch = xcd >> 1;
  const int idb = ((bid >> 3) << 1) | (xcd & 1);  // 0 .. 64*SPLIT-1
  const int slot = idb / SPLIT;
  const int chunk = idb % SPLIT;
  const int q0 = batch * TF + slot * 64 + wave * 16;
  const int kbase = chunk * CHUNK;

  __shared__ unsigned short Plds[4][16 * 72];  // per-wave P[q][kv] buffer
  unsigned short* Pw = &Plds[wave][0];

  const unsigned short* Qp = Qb + (size_t)q0 * DK;
  const unsigned short* Kp = Kb + ((size_t)batch * TF + kbase) * DK;
  const unsigned short* Vp = VT + (size_t)batch * DK * TF + kbase;

  sh8 aq[4];
#pragma unroll
  for (int dd = 0; dd < 4; ++dd)
    aq[dd] = *(const sh8*)(Qp + lr * DK + dd * 32 + lg * 8);

  const f32x4 z4 = {0.f, 0.f, 0.f, 0.f};
  f32x4 ot[8];  // ot[nb][r] = O^T[d = nb*16 + lg*4 + r][q = lr]
#pragma unroll
  for (int nb = 0; nb < 8; ++nb) ot[nb] = z4;
  float mrow = -1e30f, lrow = 0.f;  // running m/l for q = lr

  for (int kk = 0; kk < CHUNK; kk += 64) {
    // S^T = K Q^T: st[c][r] = S[q=lr][kv = kk + c*16 + lg*4 + r]
    f32x4 st[4];
#pragma unroll
    for (int c = 0; c < 4; ++c) st[c] = z4;
#pragma unroll
    for (int dd = 0; dd < 4; ++dd) {
#pragma unroll
      for (int c = 0; c < 4; ++c) {
        sh8 kb = *(const sh8*)(Kp + (size_t)(kk + c * 16 + lr) * DK + dd * 32 +
                               lg * 8);
        st[c] =
            __builtin_amdgcn_mfma_f32_16x16x32_bf16(kb, aq[dd], st[c], 0, 0, 0);
      }
    }

    // online softmax: lane owns q-row lr; combine over lanes lr+16k
    float mx = st[0][0];
#pragma unroll
    for (int c = 0; c < 4; ++c)
#pragma unroll
      for (int r = 0; r < 4; ++r) mx = fmaxf(mx, st[c][r]);
    mx = fmaxf(mx, __shfl_xor(mx, 16));
    mx = fmaxf(mx, __shfl_xor(mx, 32));
    const float mnew = fmaxf(mrow, mx);
    const float al = __expf(mrow - mnew);
    float p[4][4];
    float rs = 0.f;
#pragma unroll
    for (int c = 0; c < 4; ++c)
#pragma unroll
      for (int r = 0; r < 4; ++r) {
        p[c][r] = __expf(st[c][r] - mnew);
        rs += p[c][r];
      }
    rs += __shfl_xor(rs, 16);
    rs += __shfl_xor(rs, 32);
    lrow = lrow * al + rs;
    mrow = mnew;

#pragma unroll
    for (int nb = 0; nb < 8; ++nb)
#pragma unroll
      for (int r = 0; r < 4; ++r) ot[nb][r] *= al;

    // P[q=lr][kv]: 4 contiguous bf16 per c -> ushort4 writes
#pragma unroll
    for (int c = 0; c < 4; ++c) {
      ushort4 w;
      w.x = f2bf(p[c][0]); w.y = f2bf(p[c][1]);
      w.z = f2bf(p[c][2]); w.w = f2bf(p[c][3]);
      *(ushort4*)&Pw[lr * 72 + c * 16 + lg * 4] = w;
    }

    // O^T += V^T P^T
#pragma unroll
    for (int ks = 0; ks < 2; ++ks) {
      sh8 pa = *(const sh8*)&Pw[lr * 72 + ks * 32 + lg * 8];
#pragma unroll
      for (int nb = 0; nb < 8; ++nb) {
        sh8 vb = *(const sh8*)(Vp + (size_t)(nb * 16 + lr) * TF + kk + ks * 32 +
                               lg * 8);
        ot[nb] =
            __builtin_amdgcn_mfma_f32_16x16x32_bf16(vb, pa, ot[nb], 0, 0, 0);
      }
    }
  }

  if constexpr (SPLIT == 1) {
    const float inv = 1.0f / lrow;
#pragma unroll
    for (int nb = 0; nb < 8; ++nb) {
      float4 res = {ot[nb][0] * inv, ot[nb][1] * inv, ot[nb][2] * inv,
                    ot[nb][3] * inv};
      *(float4*)(out + (size_t)(q0 + lr) * DK + nb * 16 + lg * 4) = res;
    }
  } else {
    const int row = q0 + lr;
    if (lg == 0) {
      Mpart[(size_t)chunk * M_TOT + row] = mrow;
      Lpart[(size_t)chunk * M_TOT + row] = lrow;
    }
#pragma unroll
    for (int nb = 0; nb < 8; ++nb) {
      float4 res = {ot[nb][0], ot[nb][1], ot[nb][2], ot[nb][3]};
      *(float4*)(Opart + ((size_t)chunk * M_TOT + row) * DK + nb * 16 +
                 lg * 4) = res;
    }
  }
}

__global__ __launch_bounds__(256) void combine_kernel(
    const float* __restrict__ Opart, const float* __restrict__ Mpart,
    const float* __restrict__ Lpart, float* __restrict__ out, int split) {
  const int idx = blockIdx.x * 256 + threadIdx.x;  // M_TOT * 32
  const int row = idx >> 5;
  const int cq = (idx & 31) << 2;
  float m = -1e30f;
  for (int s = 0; s < split; ++s) m = fmaxf(m, Mpart[(size_t)s * M_TOT + row]);
  float den = 0.f;
  float4 acc = {0.f, 0.f, 0.f, 0.f};
  for (int s = 0; s < split; ++s) {
    const float w = __expf(Mpart[(size_t)s * M_TOT + row] - m);
    den += w * Lpart[(size_t)s * M_TOT + row];
    const float4 v = *(const float4*)(Opart + ((size_t)s * M_TOT + row) * DK + cq);
    acc.x += w * v.x; acc.y += w * v.y; acc.z += w * v.z; acc.w += w * v.w;
  }
  const float inv = 1.0f / den;
  float4 res = {acc.x * inv, acc.y * inv, acc.z * inv, acc.w * inv};
  *(float4*)(out + (size_t)row * DK + cq) = res;
}

extern "C" void kernel_launch(void* const* d_in, const int* in_sizes, int n_in,
                              void* d_out, int out_size, void* d_ws,
                              size_t ws_size, hipStream_t stream) {
  const float* x = (const float*)d_in[0];
  const float* Wq = (const float*)d_in[1];
  const float* bq = (const float*)d_in[2];
  const float* Wk = (const float*)d_in[3];
  const float* bk = (const float*)d_in[4];
  const float* Wv = (const float*)d_in[5];
  const float* bv = (const float*)d_in[6];
  float* out = (float*)d_out;

  unsigned short* Wt = (unsigned short*)d_ws;              // 768 KB
  unsigned short* Qb = Wt + 3 * DK * DIN;                  // 4 MB
  unsigned short* Kb = Qb + (size_t)M_TOT * DK;            // 4 MB
  unsigned short* VT = Kb + (size_t)M_TOT * DK;            // 4 MB
  float* Opart = (float*)(VT + (size_t)M_TOT * DK);        // split*8 MB
  const size_t base_bytes = 2ull * (3 * DK * DIN + 3ull * M_TOT * DK);
  const size_t per_split = (size_t)M_TOT * DK * 4 + 2ull * M_TOT * 4;

  prep_wt_kernel<<<(3 * DK * DIN) / 256, 256, 0, stream>>>(Wq, Wk, Wv, Wt);
  proj_kernel<<<M_TOT / 64, 256, 0, stream>>>(x, Wt, bq, bk, bv, Qb, Kb, VT);

  int split;
  if (ws_size >= base_bytes + 4 * per_split) split = 4;
  else if (ws_size >= base_bytes + 2 * per_split) split = 2;
  else split = 1;

  float* Mpart = Opart + (size_t)split * M_TOT * DK;
  float* Lpart = Mpart + (size_t)split * M_TOT;

  if (split == 4) {
    attn_part_kernel<4><<<256 * 4, 256, 0, stream>>>(Qb, Kb, VT, Opart, Mpart,
                                                     Lpart, out);
    combine_kernel<<<M_TOT * 32 / 256, 256, 0, stream>>>(Opart, Mpart, Lpart,
                                                         out, 4);
  } else if (split == 2) {
    attn_part_kernel<2><<<256 * 2, 256, 0, stream>>>(Qb, Kb, VT, Opart, Mpart,
                                                     Lpart, out);
    combine_kernel<<<M_TOT * 32 / 256, 256, 0, stream>>>(Opart, Mpart, Lpart,
                                                         out, 2);
  } else {
    attn_part_kernel<1><<<256, 256, 0, stream>>>(Qb, Kb, VT, nullptr, nullptr,
                                                 nullptr, out);
  }
}

// Round 6
// 153.421 us; speedup vs baseline: 2.1484x; 2.1484x over previous
//
#include <hip/hip_runtime.h>

#define TB 4
#define TF 4096
#define DIN 1024
#define DK 128
#define M_TOT (TB * TF)  // 16384

typedef __attribute__((ext_vector_type(8))) short sh8;
typedef __attribute__((ext_vector_type(4))) float f32x4;

__device__ __forceinline__ unsigned short f2bf(float f) {
  unsigned int u = __builtin_bit_cast(unsigned int, f);
  u += 0x7FFFu + ((u >> 16) & 1u);
  return (unsigned short)(u >> 16);
}

__device__ __forceinline__ unsigned int pack_bf2(float a, float b) {
  return (unsigned int)f2bf(a) | ((unsigned int)f2bf(b) << 16);
}

// Wt[p][n][k] = bf16(W_p[k][n]);  p in {q,k,v}
__global__ __launch_bounds__(256) void prep_wt_kernel(
    const float* __restrict__ Wq, const float* __restrict__ Wk,
    const float* __restrict__ Wv, unsigned short* __restrict__ Wt) {
  int idx = blockIdx.x * 256 + threadIdx.x;  // [0, 3*128*1024)
  int p = idx >> 17;
  int r = idx & 0x1FFFF;
  int n = r >> 10;
  int k = r & 1023;
  const float* W = (p == 0) ? Wq : (p == 1) ? Wk : Wv;
  Wt[idx] = f2bf(W[k * DK + n]);
}

// Fused QKV projection. Block = 64 rows of x, 4 waves each own 32 output cols
// for all 3 projections. Q is pre-scaled by 1/sqrt(128). V stored transposed.
__global__ __launch_bounds__(256) void proj_kernel(
    const float* __restrict__ x,            // [M_TOT][DIN]
    const unsigned short* __restrict__ Wt,  // [3][DK][DIN] bf16
    const float* __restrict__ bq, const float* __restrict__ bk,
    const float* __restrict__ bv,
    unsigned short* __restrict__ Qb,  // [M_TOT][DK] bf16 (pre-scaled)
    unsigned short* __restrict__ Kb,  // [M_TOT][DK] bf16
    unsigned short* __restrict__ VT)  // [TB][DK][TF] bf16
{
  const int tid = threadIdx.x;
  const int wave = tid >> 6;
  const int lane = tid & 63;
  const int lr = lane & 15;
  const int lg = lane >> 4;
  const int m0 = blockIdx.x * 64;

  f32x4 acc[3][4][2];
  const f32x4 z4 = {0.f, 0.f, 0.f, 0.f};
#pragma unroll
  for (int p = 0; p < 3; ++p)
#pragma unroll
    for (int m = 0; m < 4; ++m)
#pragma unroll
      for (int n = 0; n < 2; ++n) acc[p][m][n] = z4;

  for (int k0 = 0; k0 < DIN; k0 += 32) {
    sh8 a[4];
#pragma unroll
    for (int m = 0; m < 4; ++m) {
      const float* xp = x + (size_t)(m0 + m * 16 + lr) * DIN + k0 + lg * 8;
      float4 f0 = *(const float4*)xp;
      float4 f1 = *(const float4*)(xp + 4);
      union { sh8 v; unsigned short u[8]; } U;
      U.u[0] = f2bf(f0.x); U.u[1] = f2bf(f0.y);
      U.u[2] = f2bf(f0.z); U.u[3] = f2bf(f0.w);
      U.u[4] = f2bf(f1.x); U.u[5] = f2bf(f1.y);
      U.u[6] = f2bf(f1.z); U.u[7] = f2bf(f1.w);
      a[m] = U.v;
    }
#pragma unroll
    for (int p = 0; p < 3; ++p) {
#pragma unroll
      for (int n = 0; n < 2; ++n) {
        const int col = wave * 32 + n * 16 + lr;
        sh8 b = *(const sh8*)(Wt + ((size_t)p * DK + col) * DIN + k0 + lg * 8);
#pragma unroll
        for (int m = 0; m < 4; ++m)
          acc[p][m][n] = __builtin_amdgcn_mfma_f32_16x16x32_bf16(
              a[m], b, acc[p][m][n], 0, 0, 0);
      }
    }
  }

  const float scale = 0.08838834764831845f;  // 1/sqrt(128)
  const int b_idx = m0 >> 12;
#pragma unroll
  for (int n = 0; n < 2; ++n) {
    const int col = wave * 32 + n * 16 + lr;
    const float add_q = bq[col];
    const float add_k = bk[col];
    const float add_v = bv[col];
#pragma unroll
    for (int m = 0; m < 4; ++m) {
      const int rowbase = m0 + m * 16 + lg * 4;
#pragma unroll
      for (int r = 0; r < 4; ++r) {
        Qb[(size_t)(rowbase + r) * DK + col] =
            f2bf((acc[0][m][n][r] + add_q) * scale);
        Kb[(size_t)(rowbase + r) * DK + col] = f2bf(acc[1][m][n][r] + add_k);
      }
      const int fbase = (m0 & (TF - 1)) + m * 16 + lg * 4;
      ushort4 pv;
      pv.x = f2bf(acc[2][m][n][0] + add_v);
      pv.y = f2bf(acc[2][m][n][1] + add_v);
      pv.z = f2bf(acc[2][m][n][2] + add_v);
      pv.w = f2bf(acc[2][m][n][3] + add_v);
      *(ushort4*)(VT + ((size_t)b_idx * DK + col) * TF + fbase) = pv;
    }
  }
}

// Flash attention, split-KV. K/V staged in LDS (R3-verified), swapped-operand
// QK^T so lane owns q-row lr (R4-verified), P redistributed in-register via
// packed-bf16 shuffles (no P LDS buffer).
// LDS = 17408 (K) + 18432 (V) = 35840 B -> 4 blocks/CU.
template <int SPLIT>
__global__ __launch_bounds__(256, 4) void attn_part_kernel(
    const unsigned short* __restrict__ Qb, const unsigned short* __restrict__ Kb,
    const unsigned short* __restrict__ VT, float* __restrict__ Opart,
    float* __restrict__ Mpart, float* __restrict__ Lpart,
    float* __restrict__ out) {
  constexpr int CHUNK = TF / SPLIT;
  const int tid = threadIdx.x;
  const int lane = tid & 63;
  const int lr = lane & 15;
  const int lg = lane >> 4;

  // XCD swizzle: 2 XCDs per batch so K/V (2 MB bf16/batch) stays L2-resident.
  const int bid = blockIdx.x;
  const int xcd = bid & 7;
  const int batch = xcd >> 1;
  const int idb = ((bid >> 3) << 1) | (xcd & 1);  // 0 .. 64*SPLIT-1
  const int slot = idb / SPLIT;
  const int chunk = idb % SPLIT;
  const int wave = tid >> 6;
  const int q0 = batch * TF + slot * 64 + wave * 16;
  const int kbase = chunk * CHUNK;

  __shared__ unsigned short Klds[64 * 136];  // 64 kv rows x 128 d (pad->136)
  __shared__ unsigned short Vlds[128 * 72];  // 128 dv rows x 64 kv (pad->72)

  const unsigned short* Qp = Qb + (size_t)q0 * DK;
  const unsigned short* Kp = Kb + (size_t)batch * TF * DK;
  const unsigned short* Vp = VT + (size_t)batch * DK * TF;

  sh8 aq[4];
#pragma unroll
  for (int dd = 0; dd < 4; ++dd)
    aq[dd] = *(const sh8*)(Qp + lr * DK + dd * 32 + lg * 8);

  const f32x4 z4 = {0.f, 0.f, 0.f, 0.f};
  f32x4 ot[8];  // ot[nb][r] = O^T[d = nb*16 + lg*4 + r][q = lr]
#pragma unroll
  for (int nb = 0; nb < 8; ++nb) ot[nb] = z4;
  float mrow = -1e30f, lrow = 0.f;

  const int srcA = lr + ((lane >> 4) & 1) * 32;  // holder lg' = 2*(lg&1)
  const int srcB = srcA + 16;                    // holder lg' = 2*(lg&1)+1
  const bool chi = (lg >= 2);                    // c = 2ks + (lg>>1)

  for (int kk0 = kbase; kk0 < kbase + CHUNK; kk0 += 64) {
    __syncthreads();
#pragma unroll
    for (int i = 0; i < 4; ++i) {  // stage K tile 64x128
      int c = tid + i * 256;
      int row = c >> 4, c8 = c & 15;
      *(uint4*)&Klds[row * 136 + c8 * 8] =
          *(const uint4*)(Kp + (size_t)(kk0 + row) * DK + c8 * 8);
    }
#pragma unroll
    for (int i = 0; i < 4; ++i) {  // stage V^T tile 128x64
      int c = tid + i * 256;
      int row = c >> 3, c8 = c & 7;
      *(uint4*)&Vlds[row * 72 + c8 * 8] =
          *(const uint4*)(Vp + (size_t)row * TF + kk0 + c8 * 8);
    }
    __syncthreads();

    // S^T = K Q^T: st[c][r] = S[q=lr][kv = c*16 + lg*4 + r]
    f32x4 st[4];
#pragma unroll
    for (int c = 0; c < 4; ++c) st[c] = z4;
#pragma unroll
    for (int dd = 0; dd < 4; ++dd) {
#pragma unroll
      for (int c = 0; c < 4; ++c) {
        sh8 kb = *(const sh8*)&Klds[(c * 16 + lr) * 136 + dd * 32 + lg * 8];
        st[c] =
            __builtin_amdgcn_mfma_f32_16x16x32_bf16(kb, aq[dd], st[c], 0, 0, 0);
      }
    }

    // online softmax: lane owns q-row lr; combine over lanes lr+16,+32,+48
    float mx = st[0][0];
#pragma unroll
    for (int c = 0; c < 4; ++c)
#pragma unroll
      for (int r = 0; r < 4; ++r) mx = fmaxf(mx, st[c][r]);
    mx = fmaxf(mx, __shfl_xor(mx, 16));
    mx = fmaxf(mx, __shfl_xor(mx, 32));
    const float mnew = fmaxf(mrow, mx);
    const float al = __expf(mrow - mnew);
    float p[4][4];
    float rs = 0.f;
#pragma unroll
    for (int c = 0; c < 4; ++c)
#pragma unroll
      for (int r = 0; r < 4; ++r) {
        p[c][r] = __expf(st[c][r] - mnew);
        rs += p[c][r];
      }
    rs += __shfl_xor(rs, 16);
    rs += __shfl_xor(rs, 32);
    lrow = lrow * al + rs;
    mrow = mnew;

#pragma unroll
    for (int nb = 0; nb < 8; ++nb)
#pragma unroll
      for (int r = 0; r < 4; ++r) ot[nb][r] *= al;

    // pack P rows to bf16 pairs: up[c][h] = P[q=lr][kv=c*16+lg*4+2h+{0,1}]
    unsigned int up[4][2];
#pragma unroll
    for (int c = 0; c < 4; ++c) {
      up[c][0] = pack_bf2(p[c][0], p[c][1]);
      up[c][1] = pack_bf2(p[c][2], p[c][3]);
    }

    // O^T += V^T P^T; B-fragment pa built by cross-lane exchange:
    // lane (lr,lg) needs P[q=lr][kv=ks*32+lg*8+j], j=0..7.
#pragma unroll
    for (int ks = 0; ks < 2; ++ks) {
      unsigned int e0 = __shfl((int)up[2 * ks][0], srcA);
      unsigned int o0 = __shfl((int)up[2 * ks + 1][0], srcA);
      unsigned int e1 = __shfl((int)up[2 * ks][1], srcA);
      unsigned int o1 = __shfl((int)up[2 * ks + 1][1], srcA);
      unsigned int e2 = __shfl((int)up[2 * ks][0], srcB);
      unsigned int o2 = __shfl((int)up[2 * ks + 1][0], srcB);
      unsigned int e3 = __shfl((int)up[2 * ks][1], srcB);
      unsigned int o3 = __shfl((int)up[2 * ks + 1][1], srcB);
      union { unsigned int u[4]; sh8 v; } PA;
      PA.u[0] = chi ? o0 : e0;
      PA.u[1] = chi ? o1 : e1;
      PA.u[2] = chi ? o2 : e2;
      PA.u[3] = chi ? o3 : e3;
#pragma unroll
      for (int nb = 0; nb < 8; ++nb) {
        sh8 vb = *(const sh8*)&Vlds[(nb * 16 + lr) * 72 + ks * 32 + lg * 8];
        ot[nb] =
            __builtin_amdgcn_mfma_f32_16x16x32_bf16(vb, PA.v, ot[nb], 0, 0, 0);
      }
    }
  }

  if constexpr (SPLIT == 1) {
    const float inv = 1.0f / lrow;
#pragma unroll
    for (int nb = 0; nb < 8; ++nb) {
      float4 res = {ot[nb][0] * inv, ot[nb][1] * inv, ot[nb][2] * inv,
                    ot[nb][3] * inv};
      *(float4*)(out + (size_t)(q0 + lr) * DK + nb * 16 + lg * 4) = res;
    }
  } else {
    const int row = q0 + lr;
    if (lg == 0) {
      Mpart[(size_t)chunk * M_TOT + row] = mrow;
      Lpart[(size_t)chunk * M_TOT + row] = lrow;
    }
#pragma unroll
    for (int nb = 0; nb < 8; ++nb) {
      float4 res = {ot[nb][0], ot[nb][1], ot[nb][2], ot[nb][3]};
      *(float4*)(Opart + ((size_t)chunk * M_TOT + row) * DK + nb * 16 +
                 lg * 4) = res;
    }
  }
}

__global__ __launch_bounds__(256) void combine_kernel(
    const float* __restrict__ Opart, const float* __restrict__ Mpart,
    const float* __restrict__ Lpart, float* __restrict__ out, int split) {
  const int idx = blockIdx.x * 256 + threadIdx.x;  // M_TOT * 32
  const int row = idx >> 5;
  const int cq = (idx & 31) << 2;
  float m = -1e30f;
  for (int s = 0; s < split; ++s) m = fmaxf(m, Mpart[(size_t)s * M_TOT + row]);
  float den = 0.f;
  float4 acc = {0.f, 0.f, 0.f, 0.f};
  for (int s = 0; s < split; ++s) {
    const float w = __expf(Mpart[(size_t)s * M_TOT + row] - m);
    den += w * Lpart[(size_t)s * M_TOT + row];
    const float4 v = *(const float4*)(Opart + ((size_t)s * M_TOT + row) * DK + cq);
    acc.x += w * v.x; acc.y += w * v.y; acc.z += w * v.z; acc.w += w * v.w;
  }
  const float inv = 1.0f / den;
  float4 res = {acc.x * inv, acc.y * inv, acc.z * inv, acc.w * inv};
  *(float4*)(out + (size_t)row * DK + cq) = res;
}

extern "C" void kernel_launch(void* const* d_in, const int* in_sizes, int n_in,
                              void* d_out, int out_size, void* d_ws,
                              size_t ws_size, hipStream_t stream) {
  const float* x = (const float*)d_in[0];
  const float* Wq = (const float*)d_in[1];
  const float* bq = (const float*)d_in[2];
  const float* Wk = (const float*)d_in[3];
  const float* bk = (const float*)d_in[4];
  const float* Wv = (const float*)d_in[5];
  const float* bv = (const float*)d_in[6];
  float* out = (float*)d_out;

  unsigned short* Wt = (unsigned short*)d_ws;              // 768 KB
  unsigned short* Qb = Wt + 3 * DK * DIN;                  // 4 MB
  unsigned short* Kb = Qb + (size_t)M_TOT * DK;            // 4 MB
  unsigned short* VT = Kb + (size_t)M_TOT * DK;            // 4 MB
  float* Opart = (float*)(VT + (size_t)M_TOT * DK);        // split*8 MB
  const size_t base_bytes = 2ull * (3 * DK * DIN + 3ull * M_TOT * DK);
  const size_t per_split = (size_t)M_TOT * DK * 4 + 2ull * M_TOT * 4;

  prep_wt_kernel<<<(3 * DK * DIN) / 256, 256, 0, stream>>>(Wq, Wk, Wv, Wt);
  proj_kernel<<<M_TOT / 64, 256, 0, stream>>>(x, Wt, bq, bk, bv, Qb, Kb, VT);

  int split;
  if (ws_size >= base_bytes + 4 * per_split) split = 4;
  else if (ws_size >= base_bytes + 2 * per_split) split = 2;
  else split = 1;

  float* Mpart = Opart + (size_t)split * M_TOT * DK;
  float* Lpart = Mpart + (size_t)split * M_TOT;

  if (split == 4) {
    attn_part_kernel<4><<<256 * 4, 256, 0, stream>>>(Qb, Kb, VT, Opart, Mpart,
                                                     Lpart, out);
    combine_kernel<<<M_TOT * 32 / 256, 256, 0, stream>>>(Opart, Mpart, Lpart,
                                                         out, 4);
  } else if (split == 2) {
    attn_part_kernel<2><<<256 * 2, 256, 0, stream>>>(Qb, Kb, VT, Opart, Mpart,
                                                     Lpart, out);
    combine_kernel<<<M_TOT * 32 / 256, 256, 0, stream>>>(Opart, Mpart, Lpart,
                                                         out, 2);
  } else {
    attn_part_kernel<1><<<256, 256, 0, stream>>>(Qb, Kb, VT, nullptr, nullptr,
                                                 nullptr, out);
  }
}

// Round 7
// 128.735 us; speedup vs baseline: 2.5604x; 1.1918x over previous
//
#include <hip/hip_runtime.h>

#define TB 4
#define TF 4096
#define DIN 1024
#define DK 128
#define M_TOT (TB * TF)  // 16384

typedef __attribute__((ext_vector_type(8))) short sh8;
typedef __attribute__((ext_vector_type(4))) float f32x4;

__device__ __forceinline__ unsigned short f2bf(float f) {
  unsigned int u = __builtin_bit_cast(unsigned int, f);
  u += 0x7FFFu + ((u >> 16) & 1u);
  return (unsigned short)(u >> 16);
}

__device__ __forceinline__ unsigned int pack_bf2(float a, float b) {
  return (unsigned int)f2bf(a) | ((unsigned int)f2bf(b) << 16);
}

// Wf in MFMA-fragment order: Wf[((p*8 + t)*32 + ks)*512 + lane*8 + j]
//   = bf16(W_p[k = ks*32 + (lane>>4)*8 + j][col = t*16 + (lane&15)])
// so a wave's B-fragment load is one contiguous 1 KB read.
__global__ __launch_bounds__(256) void prep_wt_kernel(
    const float* __restrict__ Wq, const float* __restrict__ Wk,
    const float* __restrict__ Wv, unsigned short* __restrict__ Wf) {
  int idx = blockIdx.x * 256 + threadIdx.x;  // [0, 3*8*32*512)
  int j = idx & 7;
  int lane = (idx >> 3) & 63;
  int ks = (idx >> 9) & 31;
  int t = (idx >> 14) & 7;
  int p = idx >> 17;
  int col = t * 16 + (lane & 15);
  int k = ks * 32 + (lane >> 4) * 8 + j;
  const float* W = (p == 0) ? Wq : (p == 1) ? Wk : Wv;
  Wf[idx] = f2bf(W[k * DK + col]);
}

// Fused QKV projection. 512 threads = 8 waves; block = 64 rows of x.
// x tile staged in LDS as bf16 once per k-step (packing cost /8).
// Wave w owns cols w*16..w*16+15 for all 3 projections, m = 4 row-tiles.
// Q pre-scaled by 1/sqrt(128). V stored transposed.
__global__ __launch_bounds__(512, 2) void proj_kernel(
    const float* __restrict__ x,            // [M_TOT][DIN]
    const unsigned short* __restrict__ Wf,  // fragment-ordered weights
    const float* __restrict__ bq, const float* __restrict__ bk,
    const float* __restrict__ bv,
    unsigned short* __restrict__ Qb,  // [M_TOT][DK] bf16 (pre-scaled)
    unsigned short* __restrict__ Kb,  // [M_TOT][DK] bf16
    unsigned short* __restrict__ VT)  // [TB][DK][TF] bf16
{
  const int tid = threadIdx.x;
  const int wave = tid >> 6;  // 0..7 = col tile
  const int lane = tid & 63;
  const int lr = lane & 15;
  const int lg = lane >> 4;
  const int m0 = blockIdx.x * 64;
  const int col = wave * 16 + lr;

  __shared__ unsigned short Xlds[64 * 32];  // x tile bf16 [row][k]

  f32x4 acc[3][4];
  const f32x4 z4 = {0.f, 0.f, 0.f, 0.f};
#pragma unroll
  for (int p = 0; p < 3; ++p)
#pragma unroll
    for (int m = 0; m < 4; ++m) acc[p][m] = z4;

  const int xr = tid >> 3;         // 0..63
  const int xk = (tid & 7) * 4;    // 0..28

  for (int k0 = 0; k0 < DIN; k0 += 32) {
    const float4 f = *(const float4*)(x + (size_t)(m0 + xr) * DIN + k0 + xk);
    ushort4 w4;
    w4.x = f2bf(f.x); w4.y = f2bf(f.y); w4.z = f2bf(f.z); w4.w = f2bf(f.w);
    __syncthreads();  // previous tile's reads complete
    *(ushort4*)&Xlds[xr * 32 + xk] = w4;
    __syncthreads();  // tile ready

    sh8 a[4];
#pragma unroll
    for (int m = 0; m < 4; ++m)
      a[m] = *(const sh8*)&Xlds[(m * 16 + lr) * 32 + lg * 8];
#pragma unroll
    for (int p = 0; p < 3; ++p) {
      sh8 b = *(const sh8*)(Wf + ((size_t)((p * 8 + wave) * 32 + (k0 >> 5))) *
                                     512 + lane * 8);
#pragma unroll
      for (int m = 0; m < 4; ++m)
        acc[p][m] =
            __builtin_amdgcn_mfma_f32_16x16x32_bf16(a[m], b, acc[p][m], 0, 0, 0);
    }
  }

  const float scale = 0.08838834764831845f;  // 1/sqrt(128)
  const int b_idx = m0 >> 12;
  const float add_q = bq[col];
  const float add_k = bk[col];
  const float add_v = bv[col];
#pragma unroll
  for (int m = 0; m < 4; ++m) {
    const int rowbase = m0 + m * 16 + lg * 4;
#pragma unroll
    for (int r = 0; r < 4; ++r) {
      Qb[(size_t)(rowbase + r) * DK + col] =
          f2bf((acc[0][m][r] + add_q) * scale);
      Kb[(size_t)(rowbase + r) * DK + col] = f2bf(acc[1][m][r] + add_k);
    }
    const int fbase = (m0 & (TF - 1)) + m * 16 + lg * 4;
    ushort4 pv;
    pv.x = f2bf(acc[2][m][0] + add_v);
    pv.y = f2bf(acc[2][m][1] + add_v);
    pv.z = f2bf(acc[2][m][2] + add_v);
    pv.w = f2bf(acc[2][m][3] + add_v);
    *(ushort4*)(VT + ((size_t)b_idx * DK + col) * TF + fbase) = pv;
  }
}

// Flash attention, split-KV. K/V staged in LDS with T2 XOR swizzle
// (slot ^= row&7 on 16B slots, both write and read sides), swapped-operand
// QK^T (lane owns q-row lr), P redistributed in-register via packed-bf16
// shuffles. LDS = 16384 (K) + 16384 (V) = 32768 B.
template <int SPLIT>
__global__ __launch_bounds__(256, 4) void attn_part_kernel(
    const unsigned short* __restrict__ Qb, const unsigned short* __restrict__ Kb,
    const unsigned short* __restrict__ VT, float* __restrict__ Opart,
    float* __restrict__ Mpart, float* __restrict__ Lpart,
    float* __restrict__ out) {
  constexpr int CHUNK = TF / SPLIT;
  const int tid = threadIdx.x;
  const int lane = tid & 63;
  const int lr = lane & 15;
  const int lg = lane >> 4;

  // XCD swizzle: 2 XCDs per batch so K/V (2 MB bf16/batch) stays L2-resident.
  const int bid = blockIdx.x;
  const int xcd = bid & 7;
  const int batch = xcd >> 1;
  const int idb = ((bid >> 3) << 1) | (xcd & 1);  // 0 .. 64*SPLIT-1
  const int slot = idb / SPLIT;
  const int chunk = idb % SPLIT;
  const int wave = tid >> 6;
  const int q0 = batch * TF + slot * 64 + wave * 16;
  const int kbase = chunk * CHUNK;

  __shared__ unsigned short Klds[64 * 128];  // swizzled
  __shared__ unsigned short Vlds[128 * 64];  // swizzled

  const unsigned short* Qp = Qb + (size_t)q0 * DK;
  const unsigned short* Kp = Kb + (size_t)batch * TF * DK;
  const unsigned short* Vp = VT + (size_t)batch * DK * TF;

  sh8 aq[4];
#pragma unroll
  for (int dd = 0; dd < 4; ++dd)
    aq[dd] = *(const sh8*)(Qp + lr * DK + dd * 32 + lg * 8);

  const f32x4 z4 = {0.f, 0.f, 0.f, 0.f};
  f32x4 ot[8];  // ot[nb][r] = O^T[d = nb*16 + lg*4 + r][q = lr]
#pragma unroll
  for (int nb = 0; nb < 8; ++nb) ot[nb] = z4;
  float mrow = -1e30f, lrow = 0.f;

  const int srcA = lr + ((lane >> 4) & 1) * 32;  // holder lg' = 2*(lg&1)
  const int srcB = srcA + 16;                    // holder lg' = 2*(lg&1)+1
  const bool chi = (lg >= 2);                    // c = 2ks + (lg>>1)

  for (int kk0 = kbase; kk0 < kbase + CHUNK; kk0 += 64) {
    __syncthreads();
#pragma unroll
    for (int i = 0; i < 4; ++i) {  // stage K tile 64x128, swizzled
      int c = tid + i * 256;
      int row = c >> 4, c8 = c & 15;
      *(uint4*)&Klds[row * 128 + ((c8 ^ (row & 7)) << 3)] =
          *(const uint4*)(Kp + (size_t)(kk0 + row) * DK + c8 * 8);
    }
#pragma unroll
    for (int i = 0; i < 4; ++i) {  // stage V^T tile 128x64, swizzled
      int c = tid + i * 256;
      int row = c >> 3, c8 = c & 7;
      *(uint4*)&Vlds[row * 64 + ((c8 ^ (row & 7)) << 3)] =
          *(const uint4*)(Vp + (size_t)row * TF + kk0 + c8 * 8);
    }
    __syncthreads();

    // S^T = K Q^T: st[c][r] = S[q=lr][kv = c*16 + lg*4 + r]
    f32x4 st[4];
#pragma unroll
    for (int c = 0; c < 4; ++c) st[c] = z4;
#pragma unroll
    for (int dd = 0; dd < 4; ++dd) {
#pragma unroll
      for (int c = 0; c < 4; ++c) {
        sh8 kb = *(const sh8*)&Klds[(c * 16 + lr) * 128 +
                                    ((((dd << 2) + lg) ^ (lr & 7)) << 3)];
        st[c] =
            __builtin_amdgcn_mfma_f32_16x16x32_bf16(kb, aq[dd], st[c], 0, 0, 0);
      }
    }

    // online softmax: lane owns q-row lr; combine over lanes lr+16,+32,+48
    float mx = st[0][0];
#pragma unroll
    for (int c = 0; c < 4; ++c)
#pragma unroll
      for (int r = 0; r < 4; ++r) mx = fmaxf(mx, st[c][r]);
    mx = fmaxf(mx, __shfl_xor(mx, 16));
    mx = fmaxf(mx, __shfl_xor(mx, 32));
    const float mnew = fmaxf(mrow, mx);
    const float al = __expf(mrow - mnew);
    float p[4][4];
    float rs = 0.f;
#pragma unroll
    for (int c = 0; c < 4; ++c)
#pragma unroll
      for (int r = 0; r < 4; ++r) {
        p[c][r] = __expf(st[c][r] - mnew);
        rs += p[c][r];
      }
    rs += __shfl_xor(rs, 16);
    rs += __shfl_xor(rs, 32);
    lrow = lrow * al + rs;
    mrow = mnew;

#pragma unroll
    for (int nb = 0; nb < 8; ++nb)
#pragma unroll
      for (int r = 0; r < 4; ++r) ot[nb][r] *= al;

    // pack P rows to bf16 pairs: up[c][h] = P[q=lr][kv=c*16+lg*4+2h+{0,1}]
    unsigned int up[4][2];
#pragma unroll
    for (int c = 0; c < 4; ++c) {
      up[c][0] = pack_bf2(p[c][0], p[c][1]);
      up[c][1] = pack_bf2(p[c][2], p[c][3]);
    }

    // O^T += V^T P^T; B-fragment pa built by cross-lane exchange:
    // lane (lr,lg) needs P[q=lr][kv=ks*32+lg*8+j], j=0..7.
#pragma unroll
    for (int ks = 0; ks < 2; ++ks) {
      unsigned int e0 = __shfl((int)up[2 * ks][0], srcA);
      unsigned int o0 = __shfl((int)up[2 * ks + 1][0], srcA);
      unsigned int e1 = __shfl((int)up[2 * ks][1], srcA);
      unsigned int o1 = __shfl((int)up[2 * ks + 1][1], srcA);
      unsigned int e2 = __shfl((int)up[2 * ks][0], srcB);
      unsigned int o2 = __shfl((int)up[2 * ks + 1][0], srcB);
      unsigned int e3 = __shfl((int)up[2 * ks][1], srcB);
      unsigned int o3 = __shfl((int)up[2 * ks + 1][1], srcB);
      union { unsigned int u[4]; sh8 v; } PA;
      PA.u[0] = chi ? o0 : e0;
      PA.u[1] = chi ? o1 : e1;
      PA.u[2] = chi ? o2 : e2;
      PA.u[3] = chi ? o3 : e3;
#pragma unroll
      for (int nb = 0; nb < 8; ++nb) {
        sh8 vb = *(const sh8*)&Vlds[(nb * 16 + lr) * 64 +
                                    ((((ks << 2) + lg) ^ (lr & 7)) << 3)];
        ot[nb] =
            __builtin_amdgcn_mfma_f32_16x16x32_bf16(vb, PA.v, ot[nb], 0, 0, 0);
      }
    }
  }

  if constexpr (SPLIT == 1) {
    const float inv = 1.0f / lrow;
#pragma unroll
    for (int nb = 0; nb < 8; ++nb) {
      float4 res = {ot[nb][0] * inv, ot[nb][1] * inv, ot[nb][2] * inv,
                    ot[nb][3] * inv};
      *(float4*)(out + (size_t)(q0 + lr) * DK + nb * 16 + lg * 4) = res;
    }
  } else {
    const int row = q0 + lr;
    if (lg == 0) {
      Mpart[(size_t)chunk * M_TOT + row] = mrow;
      Lpart[(size_t)chunk * M_TOT + row] = lrow;
    }
#pragma unroll
    for (int nb = 0; nb < 8; ++nb) {
      float4 res = {ot[nb][0], ot[nb][1], ot[nb][2], ot[nb][3]};
      *(float4*)(Opart + ((size_t)chunk * M_TOT + row) * DK + nb * 16 +
                 lg * 4) = res;
    }
  }
}

__global__ __launch_bounds__(256) void combine_kernel(
    const float* __restrict__ Opart, const float* __restrict__ Mpart,
    const float* __restrict__ Lpart, float* __restrict__ out, int split) {
  const int idx = blockIdx.x * 256 + threadIdx.x;  // M_TOT * 32
  const int row = idx >> 5;
  const int cq = (idx & 31) << 2;
  float m = -1e30f;
  for (int s = 0; s < split; ++s) m = fmaxf(m, Mpart[(size_t)s * M_TOT + row]);
  float den = 0.f;
  float4 acc = {0.f, 0.f, 0.f, 0.f};
  for (int s = 0; s < split; ++s) {
    const float w = __expf(Mpart[(size_t)s * M_TOT + row] - m);
    den += w * Lpart[(size_t)s * M_TOT + row];
    const float4 v = *(const float4*)(Opart + ((size_t)s * M_TOT + row) * DK + cq);
    acc.x += w * v.x; acc.y += w * v.y; acc.z += w * v.z; acc.w += w * v.w;
  }
  const float inv = 1.0f / den;
  float4 res = {acc.x * inv, acc.y * inv, acc.z * inv, acc.w * inv};
  *(float4*)(out + (size_t)row * DK + cq) = res;
}

extern "C" void kernel_launch(void* const* d_in, const int* in_sizes, int n_in,
                              void* d_out, int out_size, void* d_ws,
                              size_t ws_size, hipStream_t stream) {
  const float* x = (const float*)d_in[0];
  const float* Wq = (const float*)d_in[1];
  const float* bq = (const float*)d_in[2];
  const float* Wk = (const float*)d_in[3];
  const float* bk = (const float*)d_in[4];
  const float* Wv = (const float*)d_in[5];
  const float* bv = (const float*)d_in[6];
  float* out = (float*)d_out;

  unsigned short* Wf = (unsigned short*)d_ws;              // 768 KB
  unsigned short* Qb = Wf + 3 * DK * DIN;                  // 4 MB
  unsigned short* Kb = Qb + (size_t)M_TOT * DK;            // 4 MB
  unsigned short* VT = Kb + (size_t)M_TOT * DK;            // 4 MB
  float* Opart = (float*)(VT + (size_t)M_TOT * DK);        // split*8 MB
  const size_t base_bytes = 2ull * (3 * DK * DIN + 3ull * M_TOT * DK);
  const size_t per_split = (size_t)M_TOT * DK * 4 + 2ull * M_TOT * 4;

  prep_wt_kernel<<<(3 * DK * DIN) / 256, 256, 0, stream>>>(Wq, Wk, Wv, Wf);
  proj_kernel<<<M_TOT / 64, 512, 0, stream>>>(x, Wf, bq, bk, bv, Qb, Kb, VT);

  int split;
  if (ws_size >= base_bytes + 4 * per_split) split = 4;
  else if (ws_size >= base_bytes + 2 * per_split) split = 2;
  else split = 1;

  float* Mpart = Opart + (size_t)split * M_TOT * DK;
  float* Lpart = Mpart + (size_t)split * M_TOT;

  if (split == 4) {
    attn_part_kernel<4><<<256 * 4, 256, 0, stream>>>(Qb, Kb, VT, Opart, Mpart,
                                                     Lpart, out);
    combine_kernel<<<M_TOT * 32 / 256, 256, 0, stream>>>(Opart, Mpart, Lpart,
                                                         out, 4);
  } else if (split == 2) {
    attn_part_kernel<2><<<256 * 2, 256, 0, stream>>>(Qb, Kb, VT, Opart, Mpart,
                                                     Lpart, out);
    combine_kernel<<<M_TOT * 32 / 256, 256, 0, stream>>>(Opart, Mpart, Lpart,
                                                         out, 2);
  } else {
    attn_part_kernel<1><<<256, 256, 0, stream>>>(Qb, Kb, VT, nullptr, nullptr,
                                                 nullptr, out);
  }
}

// Round 8
// 117.197 us; speedup vs baseline: 2.8125x; 1.0985x over previous
//
#include <hip/hip_runtime.h>

#define TB 4
#define TF 4096
#define DIN 1024
#define DK 128
#define M_TOT (TB * TF)  // 16384

typedef __attribute__((ext_vector_type(8))) short sh8;
typedef __attribute__((ext_vector_type(4))) float f32x4;

#if __has_builtin(__builtin_amdgcn_exp2f)
#define EXP2(x) __builtin_amdgcn_exp2f(x)
#else
#define EXP2(x) exp2f(x)
#endif

__device__ __forceinline__ unsigned short f2bf(float f) {
  unsigned int u = __builtin_bit_cast(unsigned int, f);
  u += 0x7FFFu + ((u >> 16) & 1u);
  return (unsigned short)(u >> 16);
}

__device__ __forceinline__ unsigned int pack_bf2(float a, float b) {
  return (unsigned int)f2bf(a) | ((unsigned int)f2bf(b) << 16);
}

// Wf in MFMA-fragment order: Wf[((p*8 + t)*32 + ks)*512 + lane*8 + j]
//   = bf16(W_p[k = ks*32 + (lane>>4)*8 + j][col = t*16 + (lane&15)])
__global__ __launch_bounds__(256) void prep_wt_kernel(
    const float* __restrict__ Wq, const float* __restrict__ Wk,
    const float* __restrict__ Wv, unsigned short* __restrict__ Wf) {
  int idx = blockIdx.x * 256 + threadIdx.x;  // [0, 3*8*32*512)
  int j = idx & 7;
  int lane = (idx >> 3) & 63;
  int ks = (idx >> 9) & 31;
  int t = (idx >> 14) & 7;
  int p = idx >> 17;
  int col = t * 16 + (lane & 15);
  int k = ks * 32 + (lane >> 4) * 8 + j;
  const float* W = (p == 0) ? Wq : (p == 1) ? Wk : Wv;
  Wf[idx] = f2bf(W[k * DK + col]);
}

// Fused QKV projection. 512 threads = 8 waves; block = 64 rows of x.
// x tile staged in LDS as bf16 once per k-step. Wave w owns 16 cols for all
// 3 projections. Q pre-scaled by log2(e)/sqrt(128) (softmax in base-2).
// V stored transposed.
__global__ __launch_bounds__(512, 2) void proj_kernel(
    const float* __restrict__ x,            // [M_TOT][DIN]
    const unsigned short* __restrict__ Wf,  // fragment-ordered weights
    const float* __restrict__ bq, const float* __restrict__ bk,
    const float* __restrict__ bv,
    unsigned short* __restrict__ Qb,  // [M_TOT][DK] bf16 (pre-scaled)
    unsigned short* __restrict__ Kb,  // [M_TOT][DK] bf16
    unsigned short* __restrict__ VT)  // [TB][DK][TF] bf16
{
  const int tid = threadIdx.x;
  const int wave = tid >> 6;  // 0..7 = col tile
  const int lane = tid & 63;
  const int lr = lane & 15;
  const int lg = lane >> 4;
  const int m0 = blockIdx.x * 64;
  const int col = wave * 16 + lr;

  __shared__ unsigned short Xlds[64 * 32];  // x tile bf16 [row][k]

  f32x4 acc[3][4];
  const f32x4 z4 = {0.f, 0.f, 0.f, 0.f};
#pragma unroll
  for (int p = 0; p < 3; ++p)
#pragma unroll
    for (int m = 0; m < 4; ++m) acc[p][m] = z4;

  const int xr = tid >> 3;         // 0..63
  const int xk = (tid & 7) * 4;    // 0..28

  for (int k0 = 0; k0 < DIN; k0 += 32) {
    const float4 f = *(const float4*)(x + (size_t)(m0 + xr) * DIN + k0 + xk);
    ushort4 w4;
    w4.x = f2bf(f.x); w4.y = f2bf(f.y); w4.z = f2bf(f.z); w4.w = f2bf(f.w);
    __syncthreads();  // previous tile's reads complete
    *(ushort4*)&Xlds[xr * 32 + xk] = w4;
    __syncthreads();  // tile ready

    sh8 a[4];
#pragma unroll
    for (int m = 0; m < 4; ++m)
      a[m] = *(const sh8*)&Xlds[(m * 16 + lr) * 32 + lg * 8];
#pragma unroll
    for (int p = 0; p < 3; ++p) {
      sh8 b = *(const sh8*)(Wf + ((size_t)((p * 8 + wave) * 32 + (k0 >> 5))) *
                                     512 + lane * 8);
#pragma unroll
      for (int m = 0; m < 4; ++m)
        acc[p][m] =
            __builtin_amdgcn_mfma_f32_16x16x32_bf16(a[m], b, acc[p][m], 0, 0, 0);
    }
  }

  // log2(e)/sqrt(128): softmax computed base-2 downstream
  const float scale = 0.12751744f;
  const int b_idx = m0 >> 12;
  const float add_q = bq[col];
  const float add_k = bk[col];
  const float add_v = bv[col];
#pragma unroll
  for (int m = 0; m < 4; ++m) {
    const int rowbase = m0 + m * 16 + lg * 4;
#pragma unroll
    for (int r = 0; r < 4; ++r) {
      Qb[(size_t)(rowbase + r) * DK + col] =
          f2bf((acc[0][m][r] + add_q) * scale);
      Kb[(size_t)(rowbase + r) * DK + col] = f2bf(acc[1][m][r] + add_k);
    }
    const int fbase = (m0 & (TF - 1)) + m * 16 + lg * 4;
    ushort4 pv;
    pv.x = f2bf(acc[2][m][0] + add_v);
    pv.y = f2bf(acc[2][m][1] + add_v);
    pv.z = f2bf(acc[2][m][2] + add_v);
    pv.w = f2bf(acc[2][m][3] + add_v);
    *(ushort4*)(VT + ((size_t)b_idx * DK + col) * TF + fbase) = pv;
  }
}

// Flash attention, split-KV. K/V staged in padded LDS (R6-proven),
// swapped-operand QK^T (lane owns q-row lr), in-register P exchange,
// base-2 softmax with defer-max rescale (T13, THR=11.5 log2 units).
// LDS = 17408 (K) + 18432 (V) = 35840 B -> 4 blocks/CU.
template <int SPLIT>
__global__ __launch_bounds__(256, 4) void attn_part_kernel(
    const unsigned short* __restrict__ Qb, const unsigned short* __restrict__ Kb,
    const unsigned short* __restrict__ VT, float* __restrict__ Opart,
    float* __restrict__ Mpart, float* __restrict__ Lpart,
    float* __restrict__ out) {
  constexpr int CHUNK = TF / SPLIT;
  const int tid = threadIdx.x;
  const int lane = tid & 63;
  const int lr = lane & 15;
  const int lg = lane >> 4;

  // XCD swizzle: 2 XCDs per batch so K/V (2 MB bf16/batch) stays L2-resident.
  const int bid = blockIdx.x;
  const int xcd = bid & 7;
  const int batch = xcd >> 1;
  const int idb = ((bid >> 3) << 1) | (xcd & 1);  // 0 .. 64*SPLIT-1
  const int slot = idb / SPLIT;
  const int chunk = idb % SPLIT;
  const int wave = tid >> 6;
  const int q0 = batch * TF + slot * 64 + wave * 16;
  const int kbase = chunk * CHUNK;

  __shared__ unsigned short Klds[64 * 136];  // 64 kv rows x 128 d (pad->136)
  __shared__ unsigned short Vlds[128 * 72];  // 128 dv rows x 64 kv (pad->72)

  const unsigned short* Qp = Qb + (size_t)q0 * DK;
  const unsigned short* Kp = Kb + (size_t)batch * TF * DK;
  const unsigned short* Vp = VT + (size_t)batch * DK * TF;

  sh8 aq[4];
#pragma unroll
  for (int dd = 0; dd < 4; ++dd)
    aq[dd] = *(const sh8*)(Qp + lr * DK + dd * 32 + lg * 8);

  const f32x4 z4 = {0.f, 0.f, 0.f, 0.f};
  f32x4 ot[8];  // ot[nb][r] = O^T[d = nb*16 + lg*4 + r][q = lr]
#pragma unroll
  for (int nb = 0; nb < 8; ++nb) ot[nb] = z4;
  float mrow = -1e30f, lrow = 0.f;  // m in log2 units

  const int srcA = lr + ((lane >> 4) & 1) * 32;  // holder lg' = 2*(lg&1)
  const int srcB = srcA + 16;                    // holder lg' = 2*(lg&1)+1
  const bool chi = (lg >= 2);                    // c = 2ks + (lg>>1)

  for (int kk0 = kbase; kk0 < kbase + CHUNK; kk0 += 64) {
    __syncthreads();
#pragma unroll
    for (int i = 0; i < 4; ++i) {  // stage K tile 64x128
      int c = tid + i * 256;
      int row = c >> 4, c8 = c & 15;
      *(uint4*)&Klds[row * 136 + c8 * 8] =
          *(const uint4*)(Kp + (size_t)(kk0 + row) * DK + c8 * 8);
    }
#pragma unroll
    for (int i = 0; i < 4; ++i) {  // stage V^T tile 128x64
      int c = tid + i * 256;
      int row = c >> 3, c8 = c & 7;
      *(uint4*)&Vlds[row * 72 + c8 * 8] =
          *(const uint4*)(Vp + (size_t)row * TF + kk0 + c8 * 8);
    }
    __syncthreads();

    // S^T = K Q^T: st[c][r] = S[q=lr][kv = c*16 + lg*4 + r] (log2 units)
    f32x4 st[4];
#pragma unroll
    for (int c = 0; c < 4; ++c) st[c] = z4;
#pragma unroll
    for (int dd = 0; dd < 4; ++dd) {
#pragma unroll
      for (int c = 0; c < 4; ++c) {
        sh8 kb = *(const sh8*)&Klds[(c * 16 + lr) * 136 + dd * 32 + lg * 8];
        st[c] =
            __builtin_amdgcn_mfma_f32_16x16x32_bf16(kb, aq[dd], st[c], 0, 0, 0);
      }
    }

    // online softmax (base-2): lane owns q-row lr
    float mx = st[0][0];
#pragma unroll
    for (int c = 0; c < 4; ++c)
#pragma unroll
      for (int r = 0; r < 4; ++r) mx = fmaxf(mx, st[c][r]);
    mx = fmaxf(mx, __shfl_xor(mx, 16));
    mx = fmaxf(mx, __shfl_xor(mx, 32));

    // defer-max: skip rescale while tile max stays within THR of running max
    if (!__all(mx - mrow <= 11.5f)) {
      const float mnew = fmaxf(mrow, mx);
      const float al = EXP2(mrow - mnew);
      lrow *= al;
#pragma unroll
      for (int nb = 0; nb < 8; ++nb)
#pragma unroll
        for (int r = 0; r < 4; ++r) ot[nb][r] *= al;
      mrow = mnew;
    }

    float p[4][4];
    float rs = 0.f;
#pragma unroll
    for (int c = 0; c < 4; ++c)
#pragma unroll
      for (int r = 0; r < 4; ++r) {
        p[c][r] = EXP2(st[c][r] - mrow);
        rs += p[c][r];
      }
    rs += __shfl_xor(rs, 16);
    rs += __shfl_xor(rs, 32);
    lrow += rs;

    // pack P rows to bf16 pairs: up[c][h] = P[q=lr][kv=c*16+lg*4+2h+{0,1}]
    unsigned int up[4][2];
#pragma unroll
    for (int c = 0; c < 4; ++c) {
      up[c][0] = pack_bf2(p[c][0], p[c][1]);
      up[c][1] = pack_bf2(p[c][2], p[c][3]);
    }

    // O^T += V^T P^T; B-fragment built by cross-lane exchange:
    // lane (lr,lg) needs P[q=lr][kv=ks*32+lg*8+j], j=0..7.
#pragma unroll
    for (int ks = 0; ks < 2; ++ks) {
      unsigned int e0 = __shfl((int)up[2 * ks][0], srcA);
      unsigned int o0 = __shfl((int)up[2 * ks + 1][0], srcA);
      unsigned int e1 = __shfl((int)up[2 * ks][1], srcA);
      unsigned int o1 = __shfl((int)up[2 * ks + 1][1], srcA);
      unsigned int e2 = __shfl((int)up[2 * ks][0], srcB);
      unsigned int o2 = __shfl((int)up[2 * ks + 1][0], srcB);
      unsigned int e3 = __shfl((int)up[2 * ks][1], srcB);
      unsigned int o3 = __shfl((int)up[2 * ks + 1][1], srcB);
      union { unsigned int u[4]; sh8 v; } PA;
      PA.u[0] = chi ? o0 : e0;
      PA.u[1] = chi ? o1 : e1;
      PA.u[2] = chi ? o2 : e2;
      PA.u[3] = chi ? o3 : e3;
#pragma unroll
      for (int nb = 0; nb < 8; ++nb) {
        sh8 vb = *(const sh8*)&Vlds[(nb * 16 + lr) * 72 + ks * 32 + lg * 8];
        ot[nb] =
            __builtin_amdgcn_mfma_f32_16x16x32_bf16(vb, PA.v, ot[nb], 0, 0, 0);
      }
    }
  }

  if constexpr (SPLIT == 1) {
    const float inv = 1.0f / lrow;
#pragma unroll
    for (int nb = 0; nb < 8; ++nb) {
      float4 res = {ot[nb][0] * inv, ot[nb][1] * inv, ot[nb][2] * inv,
                    ot[nb][3] * inv};
      *(float4*)(out + (size_t)(q0 + lr) * DK + nb * 16 + lg * 4) = res;
    }
  } else {
    const int row = q0 + lr;
    if (lg == 0) {
      Mpart[(size_t)chunk * M_TOT + row] = mrow;  // log2 units
      Lpart[(size_t)chunk * M_TOT + row] = lrow;
    }
#pragma unroll
    for (int nb = 0; nb < 8; ++nb) {
      float4 res = {ot[nb][0], ot[nb][1], ot[nb][2], ot[nb][3]};
      *(float4*)(Opart + ((size_t)chunk * M_TOT + row) * DK + nb * 16 +
                 lg * 4) = res;
    }
  }
}

__global__ __launch_bounds__(256) void combine_kernel(
    const float* __restrict__ Opart, const float* __restrict__ Mpart,
    const float* __restrict__ Lpart, float* __restrict__ out, int split) {
  const int idx = blockIdx.x * 256 + threadIdx.x;  // M_TOT * 32
  const int row = idx >> 5;
  const int cq = (idx & 31) << 2;
  float m = -1e30f;
  for (int s = 0; s < split; ++s) m = fmaxf(m, Mpart[(size_t)s * M_TOT + row]);
  float den = 0.f;
  float4 acc = {0.f, 0.f, 0.f, 0.f};
  for (int s = 0; s < split; ++s) {
    const float w = EXP2(Mpart[(size_t)s * M_TOT + row] - m);  // log2 units
    den += w * Lpart[(size_t)s * M_TOT + row];
    const float4 v = *(const float4*)(Opart + ((size_t)s * M_TOT + row) * DK + cq);
    acc.x += w * v.x; acc.y += w * v.y; acc.z += w * v.z; acc.w += w * v.w;
  }
  const float inv = 1.0f / den;
  float4 res = {acc.x * inv, acc.y * inv, acc.z * inv, acc.w * inv};
  *(float4*)(out + (size_t)row * DK + cq) = res;
}

extern "C" void kernel_launch(void* const* d_in, const int* in_sizes, int n_in,
                              void* d_out, int out_size, void* d_ws,
                              size_t ws_size, hipStream_t stream) {
  const float* x = (const float*)d_in[0];
  const float* Wq = (const float*)d_in[1];
  const float* bq = (const float*)d_in[2];
  const float* Wk = (const float*)d_in[3];
  const float* bk = (const float*)d_in[4];
  const float* Wv = (const float*)d_in[5];
  const float* bv = (const float*)d_in[6];
  float* out = (float*)d_out;

  unsigned short* Wf = (unsigned short*)d_ws;              // 768 KB
  unsigned short* Qb = Wf + 3 * DK * DIN;                  // 4 MB
  unsigned short* Kb = Qb + (size_t)M_TOT * DK;            // 4 MB
  unsigned short* VT = Kb + (size_t)M_TOT * DK;            // 4 MB
  float* Opart = (float*)(VT + (size_t)M_TOT * DK);        // split*8 MB
  const size_t base_bytes = 2ull * (3 * DK * DIN + 3ull * M_TOT * DK);
  const size_t per_split = (size_t)M_TOT * DK * 4 + 2ull * M_TOT * 4;

  prep_wt_kernel<<<(3 * DK * DIN) / 256, 256, 0, stream>>>(Wq, Wk, Wv, Wf);
  proj_kernel<<<M_TOT / 64, 512, 0, stream>>>(x, Wf, bq, bk, bv, Qb, Kb, VT);

  int split;
  if (ws_size >= base_bytes + 4 * per_split) split = 4;
  else if (ws_size >= base_bytes + 2 * per_split) split = 2;
  else split = 1;

  float* Mpart = Opart + (size_t)split * M_TOT * DK;
  float* Lpart = Mpart + (size_t)split * M_TOT;

  if (split == 4) {
    attn_part_kernel<4><<<256 * 4, 256, 0, stream>>>(Qb, Kb, VT, Opart, Mpart,
                                                     Lpart, out);
    combine_kernel<<<M_TOT * 32 / 256, 256, 0, stream>>>(Opart, Mpart, Lpart,
                                                         out, 4);
  } else if (split == 2) {
    attn_part_kernel<2><<<256 * 2, 256, 0, stream>>>(Qb, Kb, VT, Opart, Mpart,
                                                     Lpart, out);
    combine_kernel<<<M_TOT * 32 / 256, 256, 0, stream>>>(Opart, Mpart, Lpart,
                                                         out, 2);
  } else {
    attn_part_kernel<1><<<256, 256, 0, stream>>>(Qb, Kb, VT, nullptr, nullptr,
                                                 nullptr, out);
  }
}

// Round 9
// 109.294 us; speedup vs baseline: 3.0159x; 1.0723x over previous
//
#include <hip/hip_runtime.h>

#define TB 4
#define TF 4096
#define DIN 1024
#define DK 128
#define M_TOT (TB * TF)  // 16384

typedef __attribute__((ext_vector_type(8))) short sh8;
typedef __attribute__((ext_vector_type(4))) float f32x4;

#if __has_builtin(__builtin_amdgcn_exp2f)
#define EXP2(x) __builtin_amdgcn_exp2f(x)
#else
#define EXP2(x) exp2f(x)
#endif

__device__ __forceinline__ unsigned short f2bf(float f) {
  unsigned int u = __builtin_bit_cast(unsigned int, f);
  u += 0x7FFFu + ((u >> 16) & 1u);
  return (unsigned short)(u >> 16);
}

__device__ __forceinline__ unsigned int pack_bf2(float a, float b) {
  return (unsigned int)f2bf(a) | ((unsigned int)f2bf(b) << 16);
}

__device__ __forceinline__ float bf2f(unsigned short u) {
  unsigned int x = ((unsigned int)u) << 16;
  return __builtin_bit_cast(float, x);
}

// Wf in MFMA-fragment order: Wf[((p*8 + t)*32 + ks)*512 + lane*8 + j]
//   = bf16(W_p[k = ks*32 + (lane>>4)*8 + j][col = t*16 + (lane&15)])
__global__ __launch_bounds__(256) void prep_wt_kernel(
    const float* __restrict__ Wq, const float* __restrict__ Wk,
    const float* __restrict__ Wv, unsigned short* __restrict__ Wf) {
  int idx = blockIdx.x * 256 + threadIdx.x;  // [0, 3*8*32*512)
  int j = idx & 7;
  int lane = (idx >> 3) & 63;
  int ks = (idx >> 9) & 31;
  int t = (idx >> 14) & 7;
  int p = idx >> 17;
  int col = t * 16 + (lane & 15);
  int k = ks * 32 + (lane >> 4) * 8 + j;
  const float* W = (p == 0) ? Wq : (p == 1) ? Wk : Wv;
  Wf[idx] = f2bf(W[k * DK + col]);
}

// Fused QKV projection. 512 threads = 8 waves; block = 64 rows of x.
// x tile staged in LDS as bf16 once per k-step. Wave w owns 16 cols for all
// 3 projections. Q pre-scaled by log2(e)/sqrt(128) (softmax in base-2).
// V stored transposed.
__global__ __launch_bounds__(512, 2) void proj_kernel(
    const float* __restrict__ x,            // [M_TOT][DIN]
    const unsigned short* __restrict__ Wf,  // fragment-ordered weights
    const float* __restrict__ bq, const float* __restrict__ bk,
    const float* __restrict__ bv,
    unsigned short* __restrict__ Qb,  // [M_TOT][DK] bf16 (pre-scaled)
    unsigned short* __restrict__ Kb,  // [M_TOT][DK] bf16
    unsigned short* __restrict__ VT)  // [TB][DK][TF] bf16
{
  const int tid = threadIdx.x;
  const int wave = tid >> 6;  // 0..7 = col tile
  const int lane = tid & 63;
  const int lr = lane & 15;
  const int lg = lane >> 4;
  const int m0 = blockIdx.x * 64;
  const int col = wave * 16 + lr;

  __shared__ unsigned short Xlds[64 * 32];  // x tile bf16 [row][k]

  f32x4 acc[3][4];
  const f32x4 z4 = {0.f, 0.f, 0.f, 0.f};
#pragma unroll
  for (int p = 0; p < 3; ++p)
#pragma unroll
    for (int m = 0; m < 4; ++m) acc[p][m] = z4;

  const int xr = tid >> 3;         // 0..63
  const int xk = (tid & 7) * 4;    // 0..28

  for (int k0 = 0; k0 < DIN; k0 += 32) {
    const float4 f = *(const float4*)(x + (size_t)(m0 + xr) * DIN + k0 + xk);
    ushort4 w4;
    w4.x = f2bf(f.x); w4.y = f2bf(f.y); w4.z = f2bf(f.z); w4.w = f2bf(f.w);
    __syncthreads();  // previous tile's reads complete
    *(ushort4*)&Xlds[xr * 32 + xk] = w4;
    __syncthreads();  // tile ready

    sh8 a[4];
#pragma unroll
    for (int m = 0; m < 4; ++m)
      a[m] = *(const sh8*)&Xlds[(m * 16 + lr) * 32 + lg * 8];
#pragma unroll
    for (int p = 0; p < 3; ++p) {
      sh8 b = *(const sh8*)(Wf + ((size_t)((p * 8 + wave) * 32 + (k0 >> 5))) *
                                     512 + lane * 8);
#pragma unroll
      for (int m = 0; m < 4; ++m)
        acc[p][m] =
            __builtin_amdgcn_mfma_f32_16x16x32_bf16(a[m], b, acc[p][m], 0, 0, 0);
    }
  }

  // log2(e)/sqrt(128): softmax computed base-2 downstream
  const float scale = 0.12751744f;
  const int b_idx = m0 >> 12;
  const float add_q = bq[col];
  const float add_k = bk[col];
  const float add_v = bv[col];
#pragma unroll
  for (int m = 0; m < 4; ++m) {
    const int rowbase = m0 + m * 16 + lg * 4;
#pragma unroll
    for (int r = 0; r < 4; ++r) {
      Qb[(size_t)(rowbase + r) * DK + col] =
          f2bf((acc[0][m][r] + add_q) * scale);
      Kb[(size_t)(rowbase + r) * DK + col] = f2bf(acc[1][m][r] + add_k);
    }
    const int fbase = (m0 & (TF - 1)) + m * 16 + lg * 4;
    ushort4 pv;
    pv.x = f2bf(acc[2][m][0] + add_v);
    pv.y = f2bf(acc[2][m][1] + add_v);
    pv.z = f2bf(acc[2][m][2] + add_v);
    pv.w = f2bf(acc[2][m][3] + add_v);
    *(ushort4*)(VT + ((size_t)b_idx * DK + col) * TF + fbase) = pv;
  }
}

// Flash attention, split-KV. 8 waves/block = 128 q rows (halves staging per
// q-row). K/V staged in padded LDS, swapped-operand QK^T (lane owns q-row
// lr), in-register P exchange, base-2 softmax with defer-max (THR=11.5).
// Partials stored bf16. LDS = 17408 + 18432 = 35840 B.
template <int SPLIT>
__global__ __launch_bounds__(512, 2) void attn_part_kernel(
    const unsigned short* __restrict__ Qb, const unsigned short* __restrict__ Kb,
    const unsigned short* __restrict__ VT, unsigned short* __restrict__ Opart,
    float* __restrict__ Mpart, float* __restrict__ Lpart,
    float* __restrict__ out) {
  constexpr int CHUNK = TF / SPLIT;
  const int tid = threadIdx.x;
  const int lane = tid & 63;
  const int lr = lane & 15;
  const int lg = lane >> 4;

  // XCD swizzle: 2 XCDs per batch so K/V (2 MB bf16/batch) stays L2-resident.
  const int bid = blockIdx.x;  // grid = 128*SPLIT
  const int xcd = bid & 7;
  const int batch = xcd >> 1;
  const int idb = ((bid >> 3) << 1) | (xcd & 1);  // 0 .. 32*SPLIT-1
  const int slot = idb / SPLIT;                   // 0..31
  const int chunk = idb % SPLIT;
  const int wave = tid >> 6;  // 0..7
  const int q0 = batch * TF + slot * 128 + wave * 16;
  const int kbase = chunk * CHUNK;

  __shared__ unsigned short Klds[64 * 136];  // 64 kv rows x 128 d (pad->136)
  __shared__ unsigned short Vlds[128 * 72];  // 128 dv rows x 64 kv (pad->72)

  const unsigned short* Qp = Qb + (size_t)q0 * DK;
  const unsigned short* Kp = Kb + (size_t)batch * TF * DK;
  const unsigned short* Vp = VT + (size_t)batch * DK * TF;

  sh8 aq[4];
#pragma unroll
  for (int dd = 0; dd < 4; ++dd)
    aq[dd] = *(const sh8*)(Qp + lr * DK + dd * 32 + lg * 8);

  const f32x4 z4 = {0.f, 0.f, 0.f, 0.f};
  f32x4 ot[8];  // ot[nb][r] = O^T[d = nb*16 + lg*4 + r][q = lr]
#pragma unroll
  for (int nb = 0; nb < 8; ++nb) ot[nb] = z4;
  float mrow = -1e30f, lrow = 0.f;  // m in log2 units

  const int srcA = lr + ((lane >> 4) & 1) * 32;  // holder lg' = 2*(lg&1)
  const int srcB = srcA + 16;                    // holder lg' = 2*(lg&1)+1
  const bool chi = (lg >= 2);                    // c = 2ks + (lg>>1)

  for (int kk0 = kbase; kk0 < kbase + CHUNK; kk0 += 64) {
    __syncthreads();
#pragma unroll
    for (int i = 0; i < 2; ++i) {  // stage K tile 64x128 (512 threads)
      int c = tid + i * 512;
      int row = c >> 4, c8 = c & 15;
      *(uint4*)&Klds[row * 136 + c8 * 8] =
          *(const uint4*)(Kp + (size_t)(kk0 + row) * DK + c8 * 8);
    }
#pragma unroll
    for (int i = 0; i < 2; ++i) {  // stage V^T tile 128x64
      int c = tid + i * 512;
      int row = c >> 3, c8 = c & 7;
      *(uint4*)&Vlds[row * 72 + c8 * 8] =
          *(const uint4*)(Vp + (size_t)row * TF + kk0 + c8 * 8);
    }
    __syncthreads();

    // S^T = K Q^T: st[c][r] = S[q=lr][kv = c*16 + lg*4 + r] (log2 units)
    f32x4 st[4];
#pragma unroll
    for (int c = 0; c < 4; ++c) st[c] = z4;
#pragma unroll
    for (int dd = 0; dd < 4; ++dd) {
#pragma unroll
      for (int c = 0; c < 4; ++c) {
        sh8 kb = *(const sh8*)&Klds[(c * 16 + lr) * 136 + dd * 32 + lg * 8];
        st[c] =
            __builtin_amdgcn_mfma_f32_16x16x32_bf16(kb, aq[dd], st[c], 0, 0, 0);
      }
    }

    // online softmax (base-2): lane owns q-row lr
    float mx = st[0][0];
#pragma unroll
    for (int c = 0; c < 4; ++c)
#pragma unroll
      for (int r = 0; r < 4; ++r) mx = fmaxf(mx, st[c][r]);
    mx = fmaxf(mx, __shfl_xor(mx, 16));
    mx = fmaxf(mx, __shfl_xor(mx, 32));

    // defer-max: skip rescale while tile max stays within THR of running max
    if (!__all(mx - mrow <= 11.5f)) {
      const float mnew = fmaxf(mrow, mx);
      const float al = EXP2(mrow - mnew);
      lrow *= al;
#pragma unroll
      for (int nb = 0; nb < 8; ++nb)
#pragma unroll
        for (int r = 0; r < 4; ++r) ot[nb][r] *= al;
      mrow = mnew;
    }

    float p[4][4];
    float rs = 0.f;
#pragma unroll
    for (int c = 0; c < 4; ++c)
#pragma unroll
      for (int r = 0; r < 4; ++r) {
        p[c][r] = EXP2(st[c][r] - mrow);
        rs += p[c][r];
      }
    rs += __shfl_xor(rs, 16);
    rs += __shfl_xor(rs, 32);
    lrow += rs;

    // pack P rows to bf16 pairs: up[c][h] = P[q=lr][kv=c*16+lg*4+2h+{0,1}]
    unsigned int up[4][2];
#pragma unroll
    for (int c = 0; c < 4; ++c) {
      up[c][0] = pack_bf2(p[c][0], p[c][1]);
      up[c][1] = pack_bf2(p[c][2], p[c][3]);
    }

    // O^T += V^T P^T; B-fragment built by cross-lane exchange:
    // lane (lr,lg) needs P[q=lr][kv=ks*32+lg*8+j], j=0..7.
#pragma unroll
    for (int ks = 0; ks < 2; ++ks) {
      unsigned int e0 = __shfl((int)up[2 * ks][0], srcA);
      unsigned int o0 = __shfl((int)up[2 * ks + 1][0], srcA);
      unsigned int e1 = __shfl((int)up[2 * ks][1], srcA);
      unsigned int o1 = __shfl((int)up[2 * ks + 1][1], srcA);
      unsigned int e2 = __shfl((int)up[2 * ks][0], srcB);
      unsigned int o2 = __shfl((int)up[2 * ks + 1][0], srcB);
      unsigned int e3 = __shfl((int)up[2 * ks][1], srcB);
      unsigned int o3 = __shfl((int)up[2 * ks + 1][1], srcB);
      union { unsigned int u[4]; sh8 v; } PA;
      PA.u[0] = chi ? o0 : e0;
      PA.u[1] = chi ? o1 : e1;
      PA.u[2] = chi ? o2 : e2;
      PA.u[3] = chi ? o3 : e3;
#pragma unroll
      for (int nb = 0; nb < 8; ++nb) {
        sh8 vb = *(const sh8*)&Vlds[(nb * 16 + lr) * 72 + ks * 32 + lg * 8];
        ot[nb] =
            __builtin_amdgcn_mfma_f32_16x16x32_bf16(vb, PA.v, ot[nb], 0, 0, 0);
      }
    }
  }

  if constexpr (SPLIT == 1) {
    const float inv = 1.0f / lrow;
#pragma unroll
    for (int nb = 0; nb < 8; ++nb) {
      float4 res = {ot[nb][0] * inv, ot[nb][1] * inv, ot[nb][2] * inv,
                    ot[nb][3] * inv};
      *(float4*)(out + (size_t)(q0 + lr) * DK + nb * 16 + lg * 4) = res;
    }
  } else {
    const int row = q0 + lr;
    if (lg == 0) {
      Mpart[(size_t)chunk * M_TOT + row] = mrow;  // log2 units
      Lpart[(size_t)chunk * M_TOT + row] = lrow;
    }
#pragma unroll
    for (int nb = 0; nb < 8; ++nb) {
      ushort4 res;
      res.x = f2bf(ot[nb][0]); res.y = f2bf(ot[nb][1]);
      res.z = f2bf(ot[nb][2]); res.w = f2bf(ot[nb][3]);
      *(ushort4*)(Opart + ((size_t)chunk * M_TOT + row) * DK + nb * 16 +
                  lg * 4) = res;
    }
  }
}

__global__ __launch_bounds__(256) void combine_kernel(
    const unsigned short* __restrict__ Opart, const float* __restrict__ Mpart,
    const float* __restrict__ Lpart, float* __restrict__ out, int split) {
  const int idx = blockIdx.x * 256 + threadIdx.x;  // M_TOT * 32
  const int row = idx >> 5;
  const int cq = (idx & 31) << 2;
  float m = -1e30f;
  for (int s = 0; s < split; ++s) m = fmaxf(m, Mpart[(size_t)s * M_TOT + row]);
  float den = 0.f;
  float4 acc = {0.f, 0.f, 0.f, 0.f};
  for (int s = 0; s < split; ++s) {
    const float w = EXP2(Mpart[(size_t)s * M_TOT + row] - m);  // log2 units
    den += w * Lpart[(size_t)s * M_TOT + row];
    const ushort4 v =
        *(const ushort4*)(Opart + ((size_t)s * M_TOT + row) * DK + cq);
    acc.x += w * bf2f(v.x); acc.y += w * bf2f(v.y);
    acc.z += w * bf2f(v.z); acc.w += w * bf2f(v.w);
  }
  const float inv = 1.0f / den;
  float4 res = {acc.x * inv, acc.y * inv, acc.z * inv, acc.w * inv};
  *(float4*)(out + (size_t)row * DK + cq) = res;
}

extern "C" void kernel_launch(void* const* d_in, const int* in_sizes, int n_in,
                              void* d_out, int out_size, void* d_ws,
                              size_t ws_size, hipStream_t stream) {
  const float* x = (const float*)d_in[0];
  const float* Wq = (const float*)d_in[1];
  const float* bq = (const float*)d_in[2];
  const float* Wk = (const float*)d_in[3];
  const float* bk = (const float*)d_in[4];
  const float* Wv = (const float*)d_in[5];
  const float* bv = (const float*)d_in[6];
  float* out = (float*)d_out;

  unsigned short* Wf = (unsigned short*)d_ws;              // 768 KB
  unsigned short* Qb = Wf + 3 * DK * DIN;                  // 4 MB
  unsigned short* Kb = Qb + (size_t)M_TOT * DK;            // 4 MB
  unsigned short* VT = Kb + (size_t)M_TOT * DK;            // 4 MB
  unsigned short* Opart = VT + (size_t)M_TOT * DK;         // split*4 MB (bf16)
  const size_t base_bytes = 2ull * (3 * DK * DIN + 3ull * M_TOT * DK);
  const size_t per_split = (size_t)M_TOT * DK * 2 + 2ull * M_TOT * 4;

  prep_wt_kernel<<<(3 * DK * DIN) / 256, 256, 0, stream>>>(Wq, Wk, Wv, Wf);
  proj_kernel<<<M_TOT / 64, 512, 0, stream>>>(x, Wf, bq, bk, bv, Qb, Kb, VT);

  int split;
  if (ws_size >= base_bytes + 4 * per_split) split = 4;
  else if (ws_size >= base_bytes + 2 * per_split) split = 2;
  else split = 1;

  float* Mpart = (float*)(Opart + (size_t)split * M_TOT * DK);
  float* Lpart = Mpart + (size_t)split * M_TOT;

  if (split == 4) {
    attn_part_kernel<4><<<128 * 4, 512, 0, stream>>>(Qb, Kb, VT, Opart, Mpart,
                                                     Lpart, out);
    combine_kernel<<<M_TOT * 32 / 256, 256, 0, stream>>>(Opart, Mpart, Lpart,
                                                         out, 4);
  } else if (split == 2) {
    attn_part_kernel<2><<<128 * 2, 512, 0, stream>>>(Qb, Kb, VT, Opart, Mpart,
                                                     Lpart, out);
    combine_kernel<<<M_TOT * 32 / 256, 256, 0, stream>>>(Opart, Mpart, Lpart,
                                                         out, 2);
  } else {
    attn_part_kernel<1><<<128, 512, 0, stream>>>(Qb, Kb, VT, nullptr, nullptr,
                                                 nullptr, out);
  }
}